// Round 16
// baseline (202.453 us; speedup 1.0000x reference)
//
#include <hip/hip_runtime.h>
#include <hip/hip_bf16.h>
#include <math.h>

// Problem constants
#define BATCH 2
#define SEQ   2048
#define DMODEL 1024
#define NHEADS 16
#define DHEAD 64
#define MROWS (BATCH*SEQ)   // 4096

typedef __attribute__((ext_vector_type(8))) short bf16x8;
typedef __attribute__((ext_vector_type(4))) short bf16x4;
typedef __attribute__((ext_vector_type(4))) float f32x4;

__device__ __forceinline__ short f2bf(float f) {   // RNE float->bf16
    union { float f; unsigned u; } c; c.f = f;
    unsigned r = (c.u + 0x7fffu + ((c.u >> 16) & 1u)) >> 16;
    return (short)r;
}
__device__ __forceinline__ float bf2f(short h) {
    union { unsigned u; float f; } c; c.u = ((unsigned)(unsigned short)h) << 16;
    return c.f;
}

__device__ __forceinline__ void async_ld16(const void* g, void* l) {
    __builtin_amdgcn_global_load_lds(
        (const __attribute__((address_space(1))) unsigned*)g,
        (__attribute__((address_space(3))) unsigned*)l, 16, 0, 0);
}

// ---------------- fused prep: convert x -> bf16 AND transpose 4 weights ----------------
__global__ __launch_bounds__(256) void prep(
    const float* __restrict__ x, short* __restrict__ xhi,
    const float* __restrict__ W0, const float* __restrict__ W1,
    const float* __restrict__ W2, const float* __restrict__ W3,
    short* __restrict__ oqkv, short* __restrict__ oo)
{
    __shared__ float T[64][65];
    const int tid = threadIdx.x;
    if (blockIdx.x < 2048) {
        const int i = blockIdx.x * 256 + tid;
        const float4* p = (const float4*)x + (size_t)i * 2;
        float4 a = p[0], b = p[1];
        float v[8] = {a.x, a.y, a.z, a.w, b.x, b.y, b.z, b.w};
        bf16x8 H;
        #pragma unroll
        for (int j = 0; j < 8; ++j) H[j] = f2bf(v[j]);
        *((bf16x8*)xhi + i) = H;
        return;
    }
    const int bi = blockIdx.x - 2048;
    const int z = bi >> 8;
    const int t = bi & 255;
    const float* W = (z == 0) ? W0 : (z == 1) ? W1 : (z == 2) ? W2 : W3;
    short* out = (z < 3) ? (oqkv + (size_t)z * 1024 * 1024) : oo;
    const int n0 = (t & 15) * 64, k0 = (t >> 4) * 64;
    #pragma unroll
    for (int i = 0; i < 16; ++i) {
        const int idx = tid + i * 256;
        const int r = idx >> 6, c = idx & 63;
        T[r][c] = W[(size_t)(k0 + r) * DMODEL + n0 + c];
    }
    __syncthreads();
    #pragma unroll
    for (int i = 0; i < 4; ++i) {
        const int idx = tid + i * 256;
        const int r = idx >> 4, g = idx & 15;
        bf16x4 H;
        #pragma unroll
        for (int j = 0; j < 4; ++j)
            H[j] = f2bf(T[g * 4 + j][r]);
        *(bf16x4*)(out + (size_t)(n0 + r) * DMODEL + k0 + g * 4) = H;
    }
}

// ---------------- QKV GEMM: 64x128 tile, grid 1536, XCD-pinned n-panels ----------------
// xcd = blk&7 owns n-tiles {3*xcd..3*xcd+2}; m sweeps sequentially -> B-panel
// (768 KB) L2-resident per XCD.
__global__ __launch_bounds__(256) void qkv_gemm(
    const short* __restrict__ Ahi, const short* __restrict__ Bthi,
    const float* __restrict__ b0, const float* __restrict__ b1, const float* __restrict__ b2,
    short* __restrict__ oqh, short* __restrict__ okh, short* __restrict__ ovh,
    float qscale)
{
    __shared__ short Ah[64 * 64], Bh[128 * 64];   // 8 KB + 16 KB

    const int tid  = threadIdx.x;
    const int lane = tid & 63;
    const int w    = tid >> 6;
    const int quad = lane >> 4;
    const int l15  = lane & 15;
    const int wr   = w >> 1, wc = w & 1;

    const int blk = blockIdx.x;
    const int g   = blk >> 3;                  // 0..191
    const int nt  = (blk & 7) * 3 + (g >> 6);  // 0..23
    const int mt  = g & 63;
    const int m0  = mt * 64;
    const int n0  = nt * 128;
    const int K   = DMODEL;

    f32x4 acc[2][4] = {};

    for (int k0 = 0; k0 < K; k0 += 64) {
        __syncthreads();
        #pragma unroll
        for (int j = 0; j < 6; ++j) {
            const int base = w * 384 + j * 64;   // A/B split at 512 (wave-uniform)
            const int c = base + lane;
            if (base < 512) {
                const int row = c >> 3, pos = (c & 7) ^ (row & 7);
                async_ld16(Ahi + (size_t)(m0 + row) * K + k0 + pos * 8, Ah + base * 8);
            } else {
                const int cb = c - 512;
                const int row = cb >> 3, pos = (cb & 7) ^ (row & 7);
                async_ld16(Bthi + (size_t)(n0 + row) * K + k0 + pos * 8, Bh + (base - 512) * 8);
            }
        }
        __syncthreads();

        #pragma unroll
        for (int s = 0; s < 2; ++s) {
            bf16x8 afh[2], bfh[4];
            #pragma unroll
            for (int mi = 0; mi < 2; ++mi) {
                const int row = wr * 32 + mi * 16 + l15;
                const int pos = (s * 4 + quad) ^ (row & 7);
                afh[mi] = *(const bf16x8*)(Ah + row * 64 + pos * 8);
            }
            #pragma unroll
            for (int ni = 0; ni < 4; ++ni) {
                const int row = wc * 64 + ni * 16 + l15;
                const int pos = (s * 4 + quad) ^ (row & 7);
                bfh[ni] = *(const bf16x8*)(Bh + row * 64 + pos * 8);
            }
            #pragma unroll
            for (int mi = 0; mi < 2; ++mi)
                #pragma unroll
                for (int ni = 0; ni < 4; ++ni)
                    acc[mi][ni] = __builtin_amdgcn_mfma_f32_16x16x32_bf16(
                        afh[mi], bfh[ni], acc[mi][ni], 0, 0, 0);
        }
    }

    const int nbase = n0 + wc * 64;              // one head per wave
    const int which = nbase >> 10;               // 0=q, 1=k, 2=v (wave-uniform)
    const int hh = (nbase & 1023) >> 6;
    const int mb = m0 + wr * 32;
    const int b = mb >> 11, sbase = mb & (SEQ - 1);
    __syncthreads();   // all waves done reading Ah/Bh; reuse as scratch
    short* scr = (w < 2) ? (Ah + w * 2048) : (Bh + (w - 2) * 2048);  // 4 KB/wave

    if (which < 2) {
        const float* bias = which ? b1 : b0;
        short* dstp = which ? okh : oqh;
        const float scl = which ? 1.0f : qscale;
        #pragma unroll
        for (int mi = 0; mi < 2; ++mi)
            #pragma unroll
            for (int ni = 0; ni < 4; ++ni)
                #pragma unroll
                for (int r = 0; r < 4; ++r) {
                    const int sloc = mi * 16 + quad * 4 + r;
                    const int dloc = ni * 16 + l15;
                    const int nn = (nbase + ni * 16 + l15) & 1023;
                    scr[sloc * 64 + (((dloc >> 3) ^ (sloc & 7)) * 8) + (dloc & 7)] =
                        f2bf((acc[mi][ni][r] + bias[nn]) * scl);
                }
        #pragma unroll
        for (int i = 0; i < 4; ++i) {
            const int sloc = i * 8 + (lane >> 3);
            const int cph = (lane & 7) ^ (sloc & 7);
            bf16x8 row = *(const bf16x8*)(scr + sloc * 64 + cph * 8);
            const int dloc = (lane & 7) * 8;
            *(bf16x8*)(dstp + ((size_t)(b * NHEADS + hh) * SEQ + sbase + sloc) * DHEAD + dloc) = row;
        }
    } else {
        #pragma unroll
        for (int mi = 0; mi < 2; ++mi)
            #pragma unroll
            for (int ni = 0; ni < 4; ++ni)
                #pragma unroll
                for (int r = 0; r < 4; ++r) {
                    const int sloc = mi * 16 + quad * 4 + r;
                    const int dloc = ni * 16 + l15;
                    const int nn = (nbase + ni * 16 + l15) & 1023;
                    scr[dloc * 32 + (((sloc >> 3) ^ (dloc & 3)) * 8) + (sloc & 7)] =
                        f2bf(acc[mi][ni][r] + b2[nn]);
                }
        #pragma unroll
        for (int i = 0; i < 4; ++i) {
            const int dloc = i * 16 + (lane >> 2);
            const int cph = (lane & 3) ^ (dloc & 3);
            bf16x8 row = *(const bf16x8*)(scr + dloc * 32 + cph * 8);
            const int sg = sbase + (lane & 3) * 8;
            *(bf16x8*)(ovh + ((size_t)(b * NHEADS + hh) * DHEAD + dloc) * SEQ + sg) = row;
        }
    }
}

// ---------------- O-proj GEMM: 64x64 tile, grid 1024, XCD-pinned n-panels ----------------
__global__ __launch_bounds__(256) void ogemm(
    const short* __restrict__ Ahi, const short* __restrict__ Bthi,
    const float* __restrict__ b0, float* __restrict__ outf)
{
    __shared__ short Ah[64 * 64], Bh[64 * 64];   // 8 KB + 8 KB

    const int tid  = threadIdx.x;
    const int lane = tid & 63;
    const int w    = tid >> 6;
    const int quad = lane >> 4;
    const int l15  = lane & 15;
    const int wr   = w >> 1, wc = w & 1;

    const int blk = blockIdx.x;
    const int g   = blk >> 3;                  // 0..127
    const int nt  = (blk & 7) * 2 + (g >> 6);  // 0..15
    const int mt  = g & 63;
    const int m0  = mt * 64;
    const int n0  = nt * 64;
    const int K   = DMODEL;

    f32x4 acc[2][2] = {};

    for (int k0 = 0; k0 < K; k0 += 64) {
        __syncthreads();
        #pragma unroll
        for (int j = 0; j < 4; ++j) {
            const int base = w * 256 + j * 64;   // w<2 -> A, w>=2 -> B (uniform)
            const int c = base + lane;
            if (base < 512) {
                const int row = c >> 3, pos = (c & 7) ^ (row & 7);
                async_ld16(Ahi + (size_t)(m0 + row) * K + k0 + pos * 8, Ah + base * 8);
            } else {
                const int cb = c - 512;
                const int row = cb >> 3, pos = (cb & 7) ^ (row & 7);
                async_ld16(Bthi + (size_t)(n0 + row) * K + k0 + pos * 8, Bh + (base - 512) * 8);
            }
        }
        __syncthreads();

        #pragma unroll
        for (int s = 0; s < 2; ++s) {
            bf16x8 afh[2], bfh[2];
            #pragma unroll
            for (int mi = 0; mi < 2; ++mi) {
                const int row = wr * 32 + mi * 16 + l15;
                const int pos = (s * 4 + quad) ^ (row & 7);
                afh[mi] = *(const bf16x8*)(Ah + row * 64 + pos * 8);
            }
            #pragma unroll
            for (int ni = 0; ni < 2; ++ni) {
                const int row = wc * 32 + ni * 16 + l15;
                const int pos = (s * 4 + quad) ^ (row & 7);
                bfh[ni] = *(const bf16x8*)(Bh + row * 64 + pos * 8);
            }
            #pragma unroll
            for (int mi = 0; mi < 2; ++mi)
                #pragma unroll
                for (int ni = 0; ni < 2; ++ni)
                    acc[mi][ni] = __builtin_amdgcn_mfma_f32_16x16x32_bf16(
                        afh[mi], bfh[ni], acc[mi][ni], 0, 0, 0);
        }
    }

    #pragma unroll
    for (int mi = 0; mi < 2; ++mi)
        #pragma unroll
        for (int ni = 0; ni < 2; ++ni)
            #pragma unroll
            for (int r = 0; r < 4; ++r) {
                const int m = m0 + wr * 32 + mi * 16 + quad * 4 + r;
                const int nn = n0 + wc * 32 + ni * 16 + l15;
                outf[(size_t)m * DMODEL + nn] = acc[mi][ni][r] + b0[nn];
            }
}

// ---------------- MFMA flash attention v13: split-K x2, 24 KB LDS ----------------
// Shared per-wave Ph tile (PV for frag A then B; wave-private in-order DS).
__global__ __launch_bounds__(256) void attn_mfma(
    const short* __restrict__ Qh_g, const short* __restrict__ Kh_g,
    const short* __restrict__ Vth_g,
    short* __restrict__ op0, float* __restrict__ l0g)
{
    __shared__ short Ksh[4096];          // [key][d] swizzled, 8 KB
    __shared__ short Vsh[4096];          // [d][s] swizzled, 8 KB
    __shared__ short Ph[4][1024];        // [wave][16x64 swizzled], 8 KB

    const int tid  = threadIdx.x;
    const int lane = tid & 63;
    const int w    = tid >> 6;
    const int quad = lane >> 4;
    const int l15  = lane & 15;

    const int bh    = blockIdx.x & 31;        // XCD-local head
    const int sk    = (blockIdx.x >> 5) & 1;  // K-split half
    const int qtile = blockIdx.x >> 6;        // 0..15
    const int q0    = qtile * 128 + w * 32;
    const size_t kvb = (size_t)bh * SEQ * DHEAD;

    bf16x8 ones;
    #pragma unroll
    for (int j = 0; j < 8; ++j) ones[j] = (short)0x3f80;   // bf16 1.0

    bf16x8 qA[2], qB[2];
    {
        const size_t qrA = kvb + (size_t)(q0 + l15) * DHEAD;
        const size_t qrB = kvb + (size_t)(q0 + 16 + l15) * DHEAD;
        qA[0] = *(const bf16x8*)(Qh_g + qrA + quad * 8);
        qA[1] = *(const bf16x8*)(Qh_g + qrA + 32 + quad * 8);
        qB[0] = *(const bf16x8*)(Qh_g + qrB + quad * 8);
        qB[1] = *(const bf16x8*)(Qh_g + qrB + 32 + quad * 8);
    }

    const bool isv = (w >= 2);
    short* dst = isv ? Vsh : Ksh;
    int srow[4], spos[4];
    #pragma unroll
    for (int j = 0; j < 4; ++j) {
        const int c = (w & 1) * 256 + j * 64 + lane;
        srow[j] = c >> 3;
        spos[j] = (c & 7) ^ (srow[j] & 7);
    }

    f32x4 oA[4] = {}, oB[4] = {};
    f32x4 lAv = {}, lBv = {};

    const int kb0 = sk * (SEQ / 2), kb1 = kb0 + SEQ / 2;   // 16 iters
    for (int kb = kb0; kb < kb1; kb += 64) {
        __syncthreads();
        {
            const short* src = isv ? (Vth_g + kvb + kb) : (Kh_g + kvb + (size_t)kb * DHEAD);
            #pragma unroll
            for (int j = 0; j < 4; ++j) {
                const short* g = src + (isv ? ((size_t)srow[j] * SEQ + spos[j] * 8)
                                            : ((size_t)srow[j] * DHEAD + spos[j] * 8));
                async_ld16(g, dst + ((w & 1) * 256 + j * 64) * 8);
            }
        }
        __syncthreads();

        // ---- S^T = K Q^T for both q-fragments (K frags read once) ----
        uint2 pkB[4];   // parked packed P for frag B
        #pragma unroll
        for (int mf = 0; mf < 4; ++mf) {
            const int row = mf * 16 + l15;
            const int sw = row & 7;
            bf16x8 kh0 = *(const bf16x8*)(Ksh + row * 64 + ((quad ^ sw) * 8));
            bf16x8 kh1 = *(const bf16x8*)(Ksh + row * 64 + (((4 + quad) ^ sw) * 8));
            f32x4 cA = {}, cB = {};
            cA = __builtin_amdgcn_mfma_f32_16x16x32_bf16(kh0, qA[0], cA, 0, 0, 0);
            cA = __builtin_amdgcn_mfma_f32_16x16x32_bf16(kh1, qA[1], cA, 0, 0, 0);
            cB = __builtin_amdgcn_mfma_f32_16x16x32_bf16(kh0, qB[0], cB, 0, 0, 0);
            cB = __builtin_amdgcn_mfma_f32_16x16x32_bf16(kh1, qB[1], cB, 0, 0, 0);

            unsigned uA[4], uB[4];
            #pragma unroll
            for (int r = 0; r < 4; ++r) {
                union { float f; unsigned u; } p;
                p.f = __builtin_amdgcn_exp2f(cA[r]);
                uA[r] = p.u;
                p.f = __builtin_amdgcn_exp2f(cB[r]);
                uB[r] = p.u;
            }
            uint2 pkA;
            pkA.x = __builtin_amdgcn_perm(uA[1], uA[0], 0x07060302u);
            pkA.y = __builtin_amdgcn_perm(uA[3], uA[2], 0x07060302u);
            pkB[mf].x = __builtin_amdgcn_perm(uB[1], uB[0], 0x07060302u);
            pkB[mf].y = __builtin_amdgcn_perm(uB[3], uB[2], 0x07060302u);
            const int pc = (mf * 2 + (quad >> 1)) ^ (l15 & 7);
            const int paddr = l15 * 64 + pc * 8 + (quad & 1) * 4;
            *(uint2*)(&Ph[w][paddr]) = pkA;
        }
        // wave-private LDS: in-order within wave, no barrier needed

        const int psw = l15 & 7;
        bf16x8 pA0 = *(const bf16x8*)(&Ph[w][l15 * 64 + ((quad ^ psw) * 8)]);
        bf16x8 pA1 = *(const bf16x8*)(&Ph[w][l15 * 64 + (((4 + quad) ^ psw) * 8)]);

        lAv = __builtin_amdgcn_mfma_f32_16x16x32_bf16(pA0, ones, lAv, 0, 0, 0);
        lAv = __builtin_amdgcn_mfma_f32_16x16x32_bf16(pA1, ones, lAv, 0, 0, 0);
        #pragma unroll
        for (int nf = 0; nf < 4; ++nf) {
            const int row = nf * 16 + l15;
            const int sw = row & 7;
            bf16x8 vh0 = *(const bf16x8*)(Vsh + row * 64 + ((quad ^ sw) * 8));
            bf16x8 vh1 = *(const bf16x8*)(Vsh + row * 64 + (((4 + quad) ^ sw) * 8));
            f32x4 cA = oA[nf];
            cA = __builtin_amdgcn_mfma_f32_16x16x32_bf16(pA0, vh0, cA, 0, 0, 0);
            cA = __builtin_amdgcn_mfma_f32_16x16x32_bf16(pA1, vh1, cA, 0, 0, 0);
            oA[nf] = cA;
        }

        // ---- frag B through the same Ph (in-order DS: writes follow reads) ----
        #pragma unroll
        for (int mf = 0; mf < 4; ++mf) {
            const int pc = (mf * 2 + (quad >> 1)) ^ (l15 & 7);
            const int paddr = l15 * 64 + pc * 8 + (quad & 1) * 4;
            *(uint2*)(&Ph[w][paddr]) = pkB[mf];
        }
        bf16x8 pB0 = *(const bf16x8*)(&Ph[w][l15 * 64 + ((quad ^ psw) * 8)]);
        bf16x8 pB1 = *(const bf16x8*)(&Ph[w][l15 * 64 + (((4 + quad) ^ psw) * 8)]);

        lBv = __builtin_amdgcn_mfma_f32_16x16x32_bf16(pB0, ones, lBv, 0, 0, 0);
        lBv = __builtin_amdgcn_mfma_f32_16x16x32_bf16(pB1, ones, lBv, 0, 0, 0);
        #pragma unroll
        for (int nf = 0; nf < 4; ++nf) {
            const int row = nf * 16 + l15;
            const int sw = row & 7;
            bf16x8 vh0 = *(const bf16x8*)(Vsh + row * 64 + ((quad ^ sw) * 8));
            bf16x8 vh1 = *(const bf16x8*)(Vsh + row * 64 + (((4 + quad) ^ sw) * 8));
            f32x4 cB = oB[nf];
            cB = __builtin_amdgcn_mfma_f32_16x16x32_bf16(pB0, vh0, cB, 0, 0, 0);
            cB = __builtin_amdgcn_mfma_f32_16x16x32_bf16(pB1, vh1, cB, 0, 0, 0);
            oB[nf] = cB;
        }
    }

    // ---- epilogue: bf16 unnormalized partial O + fp32 partial l ----
    short* op = op0 + (size_t)sk * 4194304;       // partials 8 MB apart
    float* lg = l0g + sk * 65536;
    const int b = bh >> 4, hh = bh & 15;
    #pragma unroll
    for (int r = 0; r < 4; ++r) {
        const int qa = q0 + quad * 4 + r;
        if (l15 == 0) {
            lg[bh * SEQ + qa] = lAv[r];
            lg[bh * SEQ + qa + 16] = lBv[r];
        }
    }
    #pragma unroll
    for (int nf = 0; nf < 4; ++nf) {
        #pragma unroll
        for (int r = 0; r < 4; ++r) {
            const int qa = q0 + quad * 4 + r;
            const int d = nf * 16 + l15;
            op[(size_t)(b * SEQ + qa) * DMODEL + hh * DHEAD + d] = f2bf(oA[nf][r]);
            op[(size_t)(b * SEQ + qa + 16) * DMODEL + hh * DHEAD + d] = f2bf(oB[nf][r]);
        }
    }
}

// ---------------- combine: aoh = bf16((O0+O1)/(l0+l1)), bf16 inputs ----------------
__global__ __launch_bounds__(256) void combine_o(
    const short* __restrict__ op0, const float* __restrict__ l0g,
    short* __restrict__ aoh)
{
    const int i = blockIdx.x * 256 + threadIdx.x;   // 8 elems each; grid 2048
    const size_t e = (size_t)i * 8;
    const int qg = (int)(e >> 10);
    const int col = (int)(e & 1023);
    const int b = qg >> 11;
    const int q = qg & (SEQ - 1);
    const int bhq = (b * NHEADS + (col >> 6)) * SEQ + q;
    const float inv = 1.0f / (l0g[bhq] + l0g[bhq + 65536]);

    bf16x8 a0 = *((const bf16x8*)op0 + i);
    bf16x8 a1 = *((const bf16x8*)(op0 + 4194304) + i);
    bf16x8 H;
    #pragma unroll
    for (int j = 0; j < 8; ++j)
        H[j] = f2bf((bf2f(a0[j]) + bf2f(a1[j])) * inv);
    *((bf16x8*)aoh + i) = H;
}

// ---------------- launch ----------------
extern "C" void kernel_launch(void* const* d_in, const int* in_sizes, int n_in,
                              void* d_out, int out_size, void* d_ws, size_t ws_size,
                              hipStream_t stream) {
    const float* x  = (const float*)d_in[0];
    // d_in[1] = pH : softmax shift-invariant, ignored
    const float* Wq = (const float*)d_in[2];
    const float* bq = (const float*)d_in[3];
    const float* Wk = (const float*)d_in[4];
    const float* bk = (const float*)d_in[5];
    const float* Wv = (const float*)d_in[6];
    const float* bv = (const float*)d_in[7];
    const float* Wo = (const float*)d_in[8];
    const float* bo = (const float*)d_in[9];
    float* out = (float*)d_out;

    char* ws = (char*)d_ws;
    const size_t MB = 1024 * 1024;
    short* qh  = (short*)(ws + 0 * MB);      // 8 MB
    short* kh  = (short*)(ws + 16 * MB);     // 8 MB
    short* vth = (short*)(ws + 32 * MB);     // 8 MB
    short* aoh = (short*)(ws + 48 * MB);     // 8 MB
    short* op0 = (short*)(ws + 56 * MB);     // 2x8 MB bf16 partials at 56/64
    short* xhi = (short*)(ws + 64 * MB);     // 8 MB (dead after QKV GEMM)
    short* wqkv_hi = (short*)(ws + 80 * MB); // 6 MB (dead after QKV GEMM)
    float* l0g = (float*)(ws + 88 * MB);     // 2x256 KB partial l
    short* wto_hi  = (short*)(ws + 92 * MB); // 2 MB

    dim3 blk(256);

    hipLaunchKernelGGL(prep, dim3(2048 + 1024), blk, 0, stream,
                       x, xhi, Wq, Wk, Wv, Wo, wqkv_hi, wto_hi);

    const float qscale = 0.125f * 1.44269504088896f;   // fold 1/sqrt(dh)*log2(e)
    hipLaunchKernelGGL(qkv_gemm, dim3(1536), blk, 0, stream,
                       xhi, wqkv_hi, bq, bk, bv, qh, kh, vth, qscale);

    hipLaunchKernelGGL(attn_mfma, dim3(BATCH * NHEADS * (SEQ / 128) * 2), blk, 0, stream,
                       qh, kh, vth, op0, l0g);

    hipLaunchKernelGGL(combine_o, dim3(MROWS * DMODEL / 8 / 256), blk, 0, stream,
                       op0, l0g, aoh);

    hipLaunchKernelGGL(ogemm, dim3(1024), blk, 0, stream,
                       aoh, wto_hi, bo, out);
}